// Round 1
// baseline (83.875 us; speedup 1.0000x reference)
//
#include <hip/hip_runtime.h>

#define N_   256
#define IN_  32
#define OUT_ 32
#define BS_  32

// ---------------------------------------------------------------------------
// Kernel 1: y[s][q][i] = sum_{j<8} x[s, perm[8q+j], i]   (32 blocks, 1 per s)
//           block 0 also transposes w_diag -> wdT[u][c]
// ---------------------------------------------------------------------------
__global__ __launch_bounds__(256) void k_prep(const float* __restrict__ x,
                                              const int* __restrict__ perm,
                                              const float* __restrict__ w_diag,
                                              float* __restrict__ ws_y,
                                              float* __restrict__ ws_wdT) {
    const int t = threadIdx.x;
    const int s = blockIdx.x;
    __shared__ int perm_s[256];
    perm_s[t] = perm[t];
    __syncthreads();
    const float* xs = x + s * (N_ * IN_);
#pragma unroll
    for (int k = 0; k < 4; ++k) {
        const int idx = k * 256 + t;
        const int q = idx >> 5;
        const int i = idx & 31;
        float sum = 0.f;
#pragma unroll
        for (int j = 0; j < 8; ++j)
            sum += xs[perm_s[8 * q + j] * IN_ + i];
        ws_y[(s * 32 + q) * 32 + i] = sum;
    }
    if (s == 0) {
#pragma unroll
        for (int m = 0; m < 64; ++m) {
            const int idx = m * 256 + t;      // 16384 elements of w_diag
            const int c = idx >> 4;
            const int u = idx & 15;
            ws_wdT[u * 1024 + c] = w_diag[idx];
        }
    }
}

// ---------------------------------------------------------------------------
// Kernel 2: Z[s][o][u][p] = (1/256) * sum_{i,q} w_off[(o*32+i)*512 + u*32 + (q^p)] * y[s][q][i]
// grid 256 = (sg: 8 groups of 4 s) x (o: 32).  256 threads:
//   t = sh*128 + i4*16 + u   (u: 0..15, i4: i-quad 0..7, sh: s-pair 0..1)
// Each thread: w rows for its (u, 4 i's) in 128 VGPRs; y broadcast from LDS.
// ---------------------------------------------------------------------------
__global__ __launch_bounds__(256) void k_z(const float* __restrict__ w_off,
                                           const float* __restrict__ ws_y,
                                           float* __restrict__ ws_z) {
    const int t = threadIdx.x;
    const int b = blockIdx.x;
    const int o  = b & 31;
    const int sg = b >> 5;          // s-group of 4
    const int u  = t & 15;
    const int i4 = (t >> 4) & 7;
    const int sh = t >> 7;          // s-pair within group

    __shared__ float y_lds[4 * 32 * 32];     // 16 KB
    __shared__ float part[128][8];           // 4 KB reduction scratch

    // stage y for the 4 s of this group (contiguous 16 KB)
    {
        const float4* ysrc = (const float4*)(ws_y + sg * 4096);
        float4* ydst = (float4*)y_lds;
#pragma unroll
        for (int k = 0; k < 4; ++k)
            ydst[k * 256 + t] = ysrc[k * 256 + t];
    }

    // load w_off rows into registers: wv[di][q4] = w_off[c(di)*512 + u*32 + q4*4 ..+3]
    float4 wv[4][8];
    const float* wbase = w_off + ((o * 32 + i4 * 4) * 16 + u) * 32;
#pragma unroll
    for (int di = 0; di < 4; ++di)
#pragma unroll
        for (int q4 = 0; q4 < 8; ++q4)
            wv[di][q4] = *(const float4*)(wbase + di * 512 + q4 * 4);

    __syncthreads();

#define WEL(di, qq) (((const float*)&wv[di][(qq) >> 2])[(qq) & 3])

    float accs[2][2];
#pragma unroll
    for (int dsi = 0; dsi < 2; ++dsi) {
        const float* yb = y_lds + (sh * 2 + dsi) * 1024 + i4 * 4;
        float a0 = 0.f, a1 = 0.f;
#pragma unroll
        for (int q = 0; q < 32; ++q) {
            const float4 yv = *(const float4*)(yb + q * 32);
            const int q1 = q ^ 1;
            a0 += WEL(0, q)  * yv.x + WEL(1, q)  * yv.y + WEL(2, q)  * yv.z + WEL(3, q)  * yv.w;
            a1 += WEL(0, q1) * yv.x + WEL(1, q1) * yv.y + WEL(2, q1) * yv.z + WEL(3, q1) * yv.w;
        }
        accs[dsi][0] = a0;
        accs[dsi][1] = a1;
    }
#undef WEL

#pragma unroll
    for (int dsi = 0; dsi < 2; ++dsi)
#pragma unroll
        for (int p = 0; p < 2; ++p) {
            const int slot = ((sh * 2 + dsi) * 16 + u) * 2 + p;   // s_local*32 + u*2 + p
            part[slot][i4] = accs[dsi][p];
        }
    __syncthreads();

    if (t < 128) {
        float sum = 0.f;
#pragma unroll
        for (int j = 0; j < 8; ++j) sum += part[t][j];
        const int s_local = t >> 5;
        const int uu = (t >> 1) & 15;
        const int pp = t & 1;
        const int s = sg * 4 + s_local;
        ws_z[((s * 32 + o) * 16 + uu) * 2 + pp] = sum * (1.0f / 256.0f);
    }
}

// ---------------------------------------------------------------------------
// Kernel 3: epilogue.
// grid 256 = (s: 32) x (ac: 8 chunks of 32 rows a).
// out[s, perm[a], o] = b1[o] + Z[s,o,a>>4,(a>>3)&1] + sum_i x[s,perm[a],i]*wdT[a>>4][o*32+i]
// thread t: o = t&31, rg = t>>5 -> rows a = ac*32 + rg*4 + {0..3} (u,p thread-uniform)
// ---------------------------------------------------------------------------
__global__ __launch_bounds__(256) void k_out(const float* __restrict__ x,
                                             const int* __restrict__ perm,
                                             const float* __restrict__ b1,
                                             const float* __restrict__ ws_z,
                                             const float* __restrict__ ws_wdT,
                                             float* __restrict__ out) {
    const int t = threadIdx.x;
    const int b = blockIdx.x;
    const int s = b >> 3;
    const int ac = b & 7;

    __shared__ float xrow[32 * 32];          // 4 KB
    __shared__ float wdt[2][32 * 36];        // padded rows (36) to break bank conflicts
    __shared__ float z_lds[1024];            // Z[s] slice
    __shared__ int perm_lds[32];

    if (t < 32) perm_lds[t] = perm[ac * 32 + t];

    ((float4*)z_lds)[t] = ((const float4*)(ws_z + s * 1024))[t];

    {
        const int o = t >> 3;
        const int ii = (t & 7) * 4;
#pragma unroll
        for (int uu = 0; uu < 2; ++uu) {
            const float4 v = *(const float4*)(ws_wdT + (ac * 2 + uu) * 1024 + o * 32 + ii);
            *(float4*)&wdt[uu][o * 36 + ii] = v;
        }
    }
    {
        const int r = t >> 3;
        const int col = (t & 7) * 4;
        const int rowp = perm[ac * 32 + r];               // L1-hot, 8-lane shared
        const float4 v = *(const float4*)(x + (s * N_ + rowp) * IN_ + col);
        *(float4*)&xrow[r * 32 + col] = v;
    }
    __syncthreads();

    const int o = t & 31;
    const int rg = t >> 5;
    const int u_sel = rg >> 2;               // 0/1 (uniform over the 4 rows)
    const int p = (rg >> 1) & 1;             // uniform over the 4 rows
    const int u = ac * 2 + u_sel;

    float4 wreg[8];
#pragma unroll
    for (int ii = 0; ii < 8; ++ii)
        wreg[ii] = *(const float4*)&wdt[u_sel][o * 36 + ii * 4];

    const float base = b1[o] + z_lds[(o * 16 + u) * 2 + p];

#pragma unroll
    for (int dr = 0; dr < 4; ++dr) {
        const int r = rg * 4 + dr;
        const float4* xr = (const float4*)&xrow[r * 32];
        float acc = base;
#pragma unroll
        for (int ii = 0; ii < 8; ++ii) {
            const float4 xv = xr[ii];
            const float4 wv = wreg[ii];
            acc += xv.x * wv.x + xv.y * wv.y + xv.z * wv.z + xv.w * wv.w;
        }
        out[(s * N_ + perm_lds[r]) * OUT_ + o] = acc;
    }
}

// ---------------------------------------------------------------------------
extern "C" void kernel_launch(void* const* d_in, const int* in_sizes, int n_in,
                              void* d_out, int out_size, void* d_ws, size_t ws_size,
                              hipStream_t stream) {
    const float* x      = (const float*)d_in[0];   // (32, 256, 32)
    const float* w_diag = (const float*)d_in[1];   // (1024, 16)
    const float* w_off  = (const float*)d_in[2];   // (1024, 16, 32)
    const float* b1     = (const float*)d_in[3];   // (32,)
    const int*   perm   = (const int*)d_in[4];     // (256,)
    // d_in[5] = inv_permute: not needed (we scatter via perm, a bijection)

    float* out = (float*)d_out;
    float* ws = (float*)d_ws;
    float* ws_y   = ws;                 // 32768 floats (128 KB)
    float* ws_z   = ws + 32768;         // 32768 floats (128 KB)
    float* ws_wdT = ws + 65536;         // 16384 floats (64 KB)

    k_prep<<<32, 256, 0, stream>>>(x, perm, w_diag, ws_y, ws_wdT);
    k_z<<<256, 256, 0, stream>>>(w_off, ws_y, ws_z);
    k_out<<<256, 256, 0, stream>>>(x, perm, b1, ws_z, ws_wdT, out);
}

// Round 2
// 75.044 us; speedup vs baseline: 1.1177x; 1.1177x over previous
//
#include <hip/hip_runtime.h>

#define N_   256
#define IN_  32
#define OUT_ 32
#define BS_  32

// ---------------------------------------------------------------------------
// Kernel A: fused block-sum + Z.
// grid 256 = (sg: 8 groups of 4 s) x (o: 32).  256 threads.
// Phase 1: y[s'][q][i] = sum_{j<8} x[sg*4+s', perm[8q+j], i]  into LDS
//          (recomputed redundantly per-o; trivial, L2-hot)
// Phase 2: Z[s][o][u][p] = (1/256)*sum_{i,q} w_off[(o*32+i)*512+u*32+(q^p)]*y[s][q][i]
//   t = sh*128 + i4*16 + u.  w_off rows in 128 VGPRs, y broadcast from LDS.
// ---------------------------------------------------------------------------
__global__ __launch_bounds__(256) void k_yz(const float* __restrict__ x,
                                            const int* __restrict__ perm,
                                            const float* __restrict__ w_off,
                                            float* __restrict__ ws_z) {
    const int t = threadIdx.x;
    const int b = blockIdx.x;
    const int o  = b & 31;
    const int sg = b >> 5;          // s-group of 4
    const int u  = t & 15;
    const int i4 = (t >> 4) & 7;
    const int sh = t >> 7;          // s-pair within group

    __shared__ int   perm_s[256];
    __shared__ float y_lds[4 * 32 * 32];     // 16 KB
    __shared__ float part[128][8];           // 4 KB reduction scratch

    perm_s[t] = perm[t];

    // load w_off rows into registers: wv[di][q4] = w_off[c(di)*512 + u*32 + q4*4 ..+3]
    float4 wv[4][8];
    const float* wbase = w_off + ((o * 32 + i4 * 4) * 16 + u) * 32;
#pragma unroll
    for (int di = 0; di < 4; ++di)
#pragma unroll
        for (int q4 = 0; q4 < 8; ++q4)
            wv[di][q4] = *(const float4*)(wbase + di * 512 + q4 * 4);

    __syncthreads();

    // Phase 1: block sums y into LDS (coalesced 128B rows, perm broadcast)
    {
        const int i  = t & 31;
        const int qb = t >> 5;      // 0..7
#pragma unroll
        for (int sl = 0; sl < 4; ++sl) {
            const float* xs = x + (sg * 4 + sl) * (N_ * IN_);
#pragma unroll
            for (int k = 0; k < 4; ++k) {
                const int q = qb * 4 + k;
                float sum = 0.f;
#pragma unroll
                for (int j = 0; j < 8; ++j)
                    sum += xs[perm_s[8 * q + j] * IN_ + i];
                y_lds[sl * 1024 + q * 32 + i] = sum;
            }
        }
    }
    __syncthreads();

#define WEL(di, qq) (((const float*)&wv[di][(qq) >> 2])[(qq) & 3])

    float accs[2][2];
#pragma unroll
    for (int dsi = 0; dsi < 2; ++dsi) {
        const float* yb = y_lds + (sh * 2 + dsi) * 1024 + i4 * 4;
        float a0 = 0.f, a1 = 0.f;
#pragma unroll
        for (int q = 0; q < 32; ++q) {
            const float4 yv = *(const float4*)(yb + q * 32);
            const int q1 = q ^ 1;
            a0 += WEL(0, q)  * yv.x + WEL(1, q)  * yv.y + WEL(2, q)  * yv.z + WEL(3, q)  * yv.w;
            a1 += WEL(0, q1) * yv.x + WEL(1, q1) * yv.y + WEL(2, q1) * yv.z + WEL(3, q1) * yv.w;
        }
        accs[dsi][0] = a0;
        accs[dsi][1] = a1;
    }
#undef WEL

#pragma unroll
    for (int dsi = 0; dsi < 2; ++dsi)
#pragma unroll
        for (int p = 0; p < 2; ++p) {
            const int slot = ((sh * 2 + dsi) * 16 + u) * 2 + p;   // s_local*32 + u*2 + p
            part[slot][i4] = accs[dsi][p];
        }
    __syncthreads();

    if (t < 128) {
        float sum = 0.f;
#pragma unroll
        for (int j = 0; j < 8; ++j) sum += part[t][j];
        const int s_local = t >> 5;
        const int uu = (t >> 1) & 15;
        const int pp = t & 1;
        const int s = sg * 4 + s_local;
        ws_z[((s * 32 + o) * 16 + uu) * 2 + pp] = sum * (1.0f / 256.0f);
    }
}

// ---------------------------------------------------------------------------
// Kernel B: epilogue.
// grid 256 = (s: 32) x (ac: 8 chunks of 32 rows a).
// out[s, perm[a], o] = b1[o] + Z[s,o,a>>4,(a>>3)&1] + sum_i x[s,perm[a],i]*w_diag[o*32+i, a>>4]
// thread t: o = t&31, rg = t>>5 -> rows a = ac*32 + rg*4 + {0..3} (u,p thread-uniform)
// ---------------------------------------------------------------------------
__global__ __launch_bounds__(256) void k_out(const float* __restrict__ x,
                                             const int* __restrict__ perm,
                                             const float* __restrict__ w_diag,
                                             const float* __restrict__ b1,
                                             const float* __restrict__ ws_z,
                                             float* __restrict__ out) {
    const int t = threadIdx.x;
    const int b = blockIdx.x;
    const int s = b >> 3;
    const int ac = b & 7;

    __shared__ float xrow[32 * 32];          // 4 KB
    __shared__ float wdt[2][32 * 36];        // padded rows (36) to break bank conflicts
    __shared__ float z_lds[1024];            // Z[s] slice
    __shared__ int perm_lds[32];

    if (t < 32) perm_lds[t] = perm[ac * 32 + t];

    ((float4*)z_lds)[t] = ((const float4*)(ws_z + s * 1024))[t];

    {
        // wdt[uu][o*36+ii+d] = w_diag[(o*32+ii+d)*16 + ac*2+uu]  (w_diag is (1024,16))
        const int o = t >> 3;
        const int ii = (t & 7) * 4;
#pragma unroll
        for (int uu = 0; uu < 2; ++uu)
#pragma unroll
            for (int d = 0; d < 4; ++d)
                wdt[uu][o * 36 + ii + d] = w_diag[(o * 32 + ii + d) * 16 + ac * 2 + uu];
    }
    {
        const int r = t >> 3;
        const int col = (t & 7) * 4;
        const int rowp = perm[ac * 32 + r];               // L1-hot, 8-lane shared
        const float4 v = *(const float4*)(x + (s * N_ + rowp) * IN_ + col);
        *(float4*)&xrow[r * 32 + col] = v;
    }
    __syncthreads();

    const int o = t & 31;
    const int rg = t >> 5;
    const int u_sel = rg >> 2;               // 0/1 (uniform over the 4 rows)
    const int p = (rg >> 1) & 1;             // uniform over the 4 rows
    const int u = ac * 2 + u_sel;

    float4 wreg[8];
#pragma unroll
    for (int ii = 0; ii < 8; ++ii)
        wreg[ii] = *(const float4*)&wdt[u_sel][o * 36 + ii * 4];

    const float base = b1[o] + z_lds[(o * 16 + u) * 2 + p];

#pragma unroll
    for (int dr = 0; dr < 4; ++dr) {
        const int r = rg * 4 + dr;
        const float4* xr = (const float4*)&xrow[r * 32];
        float acc = base;
#pragma unroll
        for (int ii = 0; ii < 8; ++ii) {
            const float4 xv = xr[ii];
            const float4 wv = wreg[ii];
            acc += xv.x * wv.x + xv.y * wv.y + xv.z * wv.z + xv.w * wv.w;
        }
        out[(s * N_ + perm_lds[r]) * OUT_ + o] = acc;
    }
}

// ---------------------------------------------------------------------------
extern "C" void kernel_launch(void* const* d_in, const int* in_sizes, int n_in,
                              void* d_out, int out_size, void* d_ws, size_t ws_size,
                              hipStream_t stream) {
    const float* x      = (const float*)d_in[0];   // (32, 256, 32)
    const float* w_diag = (const float*)d_in[1];   // (1024, 16)
    const float* w_off  = (const float*)d_in[2];   // (1024, 16, 32)
    const float* b1     = (const float*)d_in[3];   // (32,)
    const int*   perm   = (const int*)d_in[4];     // (256,)
    // d_in[5] = inv_permute: not needed (we scatter via perm, a bijection)

    float* out = (float*)d_out;
    float* ws_z = (float*)d_ws;        // 32768 floats (128 KB)

    k_yz<<<256, 256, 0, stream>>>(x, perm, w_off, ws_z);
    k_out<<<256, 256, 0, stream>>>(x, perm, w_diag, b1, ws_z, out);
}